// Round 21
// baseline (42.301 us; speedup 1.0000x reference)
//
#include <hip/hip_runtime.h>

#define EPS 1e-5f

typedef __attribute__((ext_vector_type(4))) float f32x4;
typedef __attribute__((ext_vector_type(8))) _Float16 f16x8;
typedef __attribute__((ext_vector_type(4))) _Float16 f16x4;

// fragment-ordered tiled index: row r (16-tiled), col k (32-tiled), K = row length.
__device__ __forceinline__ int tidx(int r, int k, int K) {
    return (r >> 4) * (K << 4) + ((k >> 5) << 9) + ((r & 15) << 5) + (((k & 31) >> 3) << 3) + (k & 7);
}

#define MFMA16(a, b, c) __builtin_amdgcn_mfma_f32_16x16x32_f16(a, b, c, 0, 0, 0)

__device__ __forceinline__ f16x8 cvt8(float4 a, float4 b) {
    f16x8 h;
    h[0] = (_Float16)a.x; h[1] = (_Float16)a.y; h[2] = (_Float16)a.z; h[3] = (_Float16)a.w;
    h[4] = (_Float16)b.x; h[5] = (_Float16)b.y; h[6] = (_Float16)b.z; h[7] = (_Float16)b.w;
    return h;
}

// LPT slot -> (graph, row): 64 slots per 8-graph chunk; 0-47 long (l=384), 48-63 short.
__device__ __forceinline__ void slot_map(int s, int& g, int& r0) {
    int c = s >> 6, j = s & 63;
    if (j < 48) { g = c * 8 + 2 * (j / 12) + 1; r0 = (j % 12) << 5; }
    else        { int jj = j - 48; g = c * 8 + 2 * (jj / 4); r0 = (jj % 4) << 5; }
}

// ============ kernel 1: prep (no am pass; 320 blocks) ============
__global__ __launch_bounds__(256) void prep_conv_kernel(
    const int* __restrict__ ld,
    const float* __restrict__ Wl, const float* __restrict__ bl,
    const float* __restrict__ gl, const float* __restrict__ betal,
    const float* __restrict__ ml, const float* __restrict__ vl,
    const float* __restrict__ W1, const float* __restrict__ b1,
    const float* __restrict__ g1, const float* __restrict__ beta1,
    const float* __restrict__ m1, const float* __restrict__ v1,
    const float* __restrict__ W2, const float* __restrict__ b2,
    const float* __restrict__ g2, const float* __restrict__ beta2,
    const float* __restrict__ m2, const float* __restrict__ v2,
    int* __restrict__ offs, float* __restrict__ c1, float* __restrict__ cf,
    int* __restrict__ tg, int* __restrict__ tr, int* __restrict__ ta, int n_tasks,
    _Float16* __restrict__ W1t, _Float16* __restrict__ Wct,
    const float* __restrict__ x, _Float16* __restrict__ XTt,
    _Float16* __restrict__ xh_t, int M)
{
    __shared__ __align__(16) _Float16 Tt[128][80];
    int t = threadIdx.x;
    if (blockIdx.x < 256) {
        int m0 = blockIdx.x * 64;
        int gg = 0, off = 0;
        while (m0 >= off + ld[gg]) { off += ld[gg]; ++gg; }
        int l = ld[gg];
        #pragma unroll
        for (int p = 0; p < 8; ++p) {
            int idx = t + p * 256;
            int m = idx >> 5;
            int f = (idx & 31) * 4;
            float4 v = *(const float4*)&x[(size_t)(m0 + m) * 128 + f];
            Tt[f + 0][m] = (_Float16)v.x; Tt[f + 1][m] = (_Float16)v.y;
            Tt[f + 2][m] = (_Float16)v.z; Tt[f + 3][m] = (_Float16)v.w;
            f16x4 h;
            h[0] = (_Float16)v.x; h[1] = (_Float16)v.y;
            h[2] = (_Float16)v.z; h[3] = (_Float16)v.w;
            *(f16x4*)&xh_t[tidx(m0 + m, f, 128)] = h;
        }
        __syncthreads();
        #pragma unroll
        for (int p = 0; p < 4; ++p) {
            int idx = t + p * 256;
            int f = idx >> 3;
            int m8 = (idx & 7) * 8;
            int kl = m0 - off + m8;
            uint4 v = *(const uint4*)&Tt[f][m8];
            *(uint4*)&XTt[off * 128 + tidx(f, kl, l)] = v;
        }
    } else {
        int b = blockIdx.x - 256;
        int gt = b * 256 + t;
        const int gsize = 64 * 256;
        if (b == 0) {
            if (t < 64) {
                int s = 0;
                for (int i = 0; i < t; ++i) s += ld[i];
                offs[t] = s;
            }
            if (t < 128) {
                float s1 = g1[t] * rsqrtf(v1[t] + EPS);
                c1[t] = (b1[t] - m1[t]) * s1 + beta1[t];
            }
            if (t < 256) {
                float s2 = g2[t] * rsqrtf(v2[t] + EPS);
                float sl = gl[t] * rsqrtf(vl[t] + EPS);
                cf[t] = (b2[t] - m2[t]) * s2 + beta2[t] + (bl[t] - ml[t]) * sl + betal[t];
            }
            for (int s = t; s < n_tasks; s += 256) {
                int g, r0;
                slot_map(s, g, r0);
                int amo = 0;
                for (int gg2 = 0; gg2 < g; ++gg2) { int L = ld[gg2]; amo += L * L; }
                tg[s] = g;
                tr[s] = r0;
                ta[s] = amo;
            }
        }
        for (int idx = gt; idx < 128 * 128; idx += gsize) {
            int n = idx >> 7, k = idx & 127;
            float s1 = g1[n] * rsqrtf(v1[n] + EPS);
            W1t[tidx(n, k, 128)] = (_Float16)(W1[idx] * s1);
        }
        for (int idx = gt; idx < 256 * 256; idx += gsize) {
            int n = idx >> 8, k = idx & 255;
            float v;
            if (k < 128) {
                float s2 = g2[n] * rsqrtf(v2[n] + EPS);
                v = W2[n * 128 + k] * s2;
            } else {
                float sl = gl[n] * rsqrtf(vl[n] + EPS);
                v = Wl[n * 128 + (k - 128)] * sl;
            }
            Wct[tidx(n, k, 256)] = (_Float16)v;
        }
    }
}

// ============ kernel 2: fused agg1 + lin1 -> H2Tt; B staged from RAW fp32 am,
//              converted fragments side-stored to amt for fused2 ============
__global__ __launch_bounds__(512) void fused1s_kernel(
    const float* __restrict__ am, const _Float16* __restrict__ XTt,
    const int* __restrict__ ld, const int* __restrict__ offs,
    const int* __restrict__ tg, const int* __restrict__ tr, const int* __restrict__ ta,
    const _Float16* __restrict__ W1t, const float* __restrict__ bias,
    _Float16* __restrict__ amt, _Float16* __restrict__ H2Tt)
{
    int task = ((blockIdx.x & 7) << 6) + (blockIdx.x >> 3);
    int g = tg[task];
    int l = ld[g];
    int off = offs[g];

    int tid = threadIdx.x;
    int lane = tid & 63;
    int w = tid >> 6;            // 0..7 = A-feat-tile
    int l15 = lane & 15;
    int l4 = lane >> 4;

    __shared__ __align__(16) _Float16 Ast[2][4096];
    __shared__ __align__(16) _Float16 Bst[2][1024];
    __shared__ __align__(16) _Float16 Hs[32][136];

    const int ts = l << 4;
    const int nk = l >> 5;                       // 4 or 12
    const int lane_off = (l15 << 5) + (l4 << 3);
    const int rdo = lane_off ^ ((l15 & 7) << 3); // swizzled read offset

    int idx63 = tid & 63;
    int wr = idx63 >> 2, wc = idx63 & 3;
    int wt = (wr << 5) + (wc << 3);
    int wts = wt ^ ((wr & 7) << 3);
    const int dstA = ((tid >> 6) << 9) + wts;
    const int dstB = (((tid >> 6) & 1) << 9) + wts;
    const bool isB = tid < 128;

    const _Float16* sa = XTt + off * 128 + (tid >> 6) * ts + (idx63 << 3);
    // raw fp32 am source for this thread's B element (row = task row + rt*16 + wr)
    const float* sbf = am + (size_t)g * 262144
        + (size_t)(tr[task] + (((tid >> 6) & 1) << 4) + wr) * 512 + (wc << 3);
    // converted-fragment destination in amt (consumed by fused2)
    _Float16* sbw = amt + ta[task]
        + ((tr[task] >> 4) + ((tid >> 6) & 1)) * ts + wt;

    f32x4 acc0 = {0.f, 0.f, 0.f, 0.f}, acc1 = acc0;
    {
        uint4 cur_a = *(const uint4*)(sa);
        float4 cb0, cb1, nb0, nb1;
        if (isB) { cb0 = *(const float4*)(sbf); cb1 = *(const float4*)(sbf + 4); }
        uint4 nxt_a = *(const uint4*)(sa + 512);
        if (isB) { nb0 = *(const float4*)(sbf + 32); nb1 = *(const float4*)(sbf + 36); }
        *(uint4*)&Ast[0][dstA] = cur_a;
        if (isB) {
            f16x8 hb = cvt8(cb0, cb1);
            *(f16x8*)&Bst[0][dstB] = hb;
            *(f16x8*)(sbw) = hb;
        }
        __syncthreads();
        for (int s = 0; s < nk; s += 2) {
            uint4 fa; float4 fb0, fb1;
            if (s + 2 < nk) {
                fa = *(const uint4*)(sa + ((s + 2) << 9));
                if (isB) {
                    fb0 = *(const float4*)(sbf + ((s + 2) << 5));
                    fb1 = *(const float4*)(sbf + ((s + 2) << 5) + 4);
                }
            }
            {
                f16x8 a  = *(const f16x8*)&Ast[0][(w << 9) + rdo];
                f16x8 b0 = *(const f16x8*)&Bst[0][rdo];
                f16x8 b1 = *(const f16x8*)&Bst[0][512 + rdo];
                acc0 = MFMA16(a, b0, acc0);
                acc1 = MFMA16(a, b1, acc1);
            }
            *(uint4*)&Ast[1][dstA] = nxt_a;
            if (isB) {
                f16x8 hb = cvt8(nb0, nb1);
                *(f16x8*)&Bst[1][dstB] = hb;
                *(f16x8*)(sbw + ((s + 1) << 9)) = hb;
            }
            __syncthreads();
            if (s + 3 < nk) {
                nxt_a = *(const uint4*)(sa + ((s + 3) << 9));
                if (isB) {
                    nb0 = *(const float4*)(sbf + ((s + 3) << 5));
                    nb1 = *(const float4*)(sbf + ((s + 3) << 5) + 4);
                }
            }
            {
                f16x8 a  = *(const f16x8*)&Ast[1][(w << 9) + rdo];
                f16x8 b0 = *(const f16x8*)&Bst[1][rdo];
                f16x8 b1 = *(const f16x8*)&Bst[1][512 + rdo];
                acc0 = MFMA16(a, b0, acc0);
                acc1 = MFMA16(a, b1, acc1);
            }
            if (s + 2 < nk) {
                *(uint4*)&Ast[0][dstA] = fa;
                if (isB) {
                    f16x8 hb = cvt8(fb0, fb1);
                    *(f16x8*)&Bst[0][dstB] = hb;
                    *(f16x8*)(sbw + ((s + 2) << 9)) = hb;
                }
                __syncthreads();
            }
        }
    }

    // spill h1: feat = w*16 + l4*4 + r; rows l15 (acc0) / 16+l15 (acc1)
    {
        f16x4 o0, o1;
        #pragma unroll
        for (int r = 0; r < 4; ++r) { o0[r] = (_Float16)acc0[r]; o1[r] = (_Float16)acc1[r]; }
        *(f16x4*)&Hs[l15][w * 16 + (l4 << 2)] = o0;
        *(f16x4*)&Hs[16 + l15][w * 16 + (l4 << 2)] = o1;
    }
    __syncthreads();

    // phase B: K=128, wave w owns out-feat tile w (16 feats), 32 rows
    const _Float16* wbase = W1t + w * 2048 + lane_off;
    f32x4 e0 = {0.f, 0.f, 0.f, 0.f}, e1 = e0;
    #pragma unroll
    for (int s = 0; s < 4; ++s) {
        int ho = (s << 5) + (l4 << 3);
        f16x8 a0 = *(const f16x8*)&Hs[l15][ho];
        f16x8 a1 = *(const f16x8*)&Hs[16 + l15][ho];
        f16x8 b  = *(const f16x8*)(wbase + (s << 9));
        e0 = MFMA16(a0, b, e0);
        e1 = MFMA16(a1, b, e1);
    }
    int hb = off * 128;
    int trb = tr[task];
    int n = w * 16 + l15;
    float bv = bias[n];
    {
        f16x4 o;
        #pragma unroll
        for (int r = 0; r < 4; ++r) {
            float v = e0[r] + bv;
            o[r] = (_Float16)(v > 0.f ? v : 0.f);
        }
        *(f16x4*)&H2Tt[hb + tidx(n, trb + (l4 << 2), l)] = o;
    }
    {
        f16x4 o;
        #pragma unroll
        for (int r = 0; r < 4; ++r) {
            float v = e1[r] + bv;
            o[r] = (_Float16)(v > 0.f ? v : 0.f);
        }
        *(f16x4*)&H2Tt[hb + tidx(n, trb + 16 + (l4 << 2), l)] = o;
    }
}

// staged phase A (fp16 B from amt) — used by fused2
#define STAGED_A()                                                            \
    {                                                                         \
        uint4 cur_a = *(const uint4*)(sa);                                    \
        uint4 cur_b; if (isB) cur_b = *(const uint4*)(sb);                    \
        uint4 nxt_a = *(const uint4*)(sa + 512);                              \
        uint4 nxt_b; if (isB) nxt_b = *(const uint4*)(sb + 512);              \
        *(uint4*)&Ast[0][dstA] = cur_a;                                       \
        if (isB) *(uint4*)&Bst[0][dstB] = cur_b;                              \
        __syncthreads();                                                      \
        for (int s = 0; s < nk; s += 2) {                                     \
            uint4 fa, fb;                                                     \
            if (s + 2 < nk) {                                                 \
                fa = *(const uint4*)(sa + ((s + 2) << 9));                    \
                if (isB) fb = *(const uint4*)(sb + ((s + 2) << 9));           \
            }                                                                 \
            {                                                                 \
                f16x8 a  = *(const f16x8*)&Ast[0][(w << 9) + rdo];            \
                f16x8 b0 = *(const f16x8*)&Bst[0][rdo];                       \
                f16x8 b1 = *(const f16x8*)&Bst[0][512 + rdo];                 \
                acc0 = MFMA16(a, b0, acc0);                                   \
                acc1 = MFMA16(a, b1, acc1);                                   \
            }                                                                 \
            *(uint4*)&Ast[1][dstA] = nxt_a;                                   \
            if (isB) *(uint4*)&Bst[1][dstB] = nxt_b;                          \
            __syncthreads();                                                  \
            if (s + 3 < nk) {                                                 \
                nxt_a = *(const uint4*)(sa + ((s + 3) << 9));                 \
                if (isB) nxt_b = *(const uint4*)(sb + ((s + 3) << 9));        \
            }                                                                 \
            {                                                                 \
                f16x8 a  = *(const f16x8*)&Ast[1][(w << 9) + rdo];            \
                f16x8 b0 = *(const f16x8*)&Bst[1][rdo];                       \
                f16x8 b1 = *(const f16x8*)&Bst[1][512 + rdo];                 \
                acc0 = MFMA16(a, b0, acc0);                                   \
                acc1 = MFMA16(a, b1, acc1);                                   \
            }                                                                 \
            if (s + 2 < nk) {                                                 \
                *(uint4*)&Ast[0][dstA] = fa;                                  \
                if (isB) *(uint4*)&Bst[0][dstB] = fb;                         \
                __syncthreads();                                              \
            }                                                                 \
        }                                                                     \
    }

// ============ kernel 3: fused agg2 + final -> out fp32 (identical to round-20) ============
__global__ __launch_bounds__(512) void fused2s_kernel(
    const _Float16* __restrict__ amt, const _Float16* __restrict__ H2Tt,
    const int* __restrict__ ld, const int* __restrict__ offs,
    const int* __restrict__ tg, const int* __restrict__ tr, const int* __restrict__ ta,
    const _Float16* __restrict__ xh_t, const _Float16* __restrict__ Wct,
    const float* __restrict__ bias, float* __restrict__ out)
{
    int task = ((blockIdx.x & 7) << 6) + (blockIdx.x >> 3);
    int g = tg[task];
    int l = ld[g];
    int off = offs[g];

    int tid = threadIdx.x;
    int lane = tid & 63;
    int w = tid >> 6;
    int l15 = lane & 15;
    int l4 = lane >> 4;

    __shared__ __align__(16) _Float16 Ast[2][4096];
    __shared__ __align__(16) _Float16 Bst[2][1024];
    __shared__ __align__(16) _Float16 Hs[32][136];

    const int ts = l << 4;
    const int nk = l >> 5;
    const int lane_off = (l15 << 5) + (l4 << 3);
    const int rdo = lane_off ^ ((l15 & 7) << 3);

    int idx63 = tid & 63;
    int wr = idx63 >> 2, wc = idx63 & 3;
    int wt = (wr << 5) + (wc << 3);
    int wts = wt ^ ((wr & 7) << 3);
    const int dstA = ((tid >> 6) << 9) + wts;
    const int dstB = (((tid >> 6) & 1) << 9) + wts;
    const bool isB = tid < 128;

    const _Float16* sa = H2Tt + off * 128 + (tid >> 6) * ts + (idx63 << 3);
    const _Float16* sb = amt + ta[task]
        + ((tr[task] >> 4) + ((tid >> 6) & 1)) * ts + (idx63 << 3);

    f32x4 acc0 = {0.f, 0.f, 0.f, 0.f}, acc1 = acc0;
    STAGED_A()

    {
        f16x4 o0, o1;
        #pragma unroll
        for (int r = 0; r < 4; ++r) { o0[r] = (_Float16)acc0[r]; o1[r] = (_Float16)acc1[r]; }
        *(f16x4*)&Hs[l15][w * 16 + (l4 << 2)] = o0;
        *(f16x4*)&Hs[16 + l15][w * 16 + (l4 << 2)] = o1;
    }
    __syncthreads();

    // phase B: K=256 ([h3 | x]), wave w owns out-feat tiles {2w, 2w+1}, 32 rows
    int gmb = off + tr[task];
    const _Float16* wb0 = Wct + (w * 2) * 4096 + lane_off;
    const _Float16* wb1 = wb0 + 4096;
    const _Float16* xp0 = xh_t + (gmb >> 4) * 2048 + lane_off;
    const _Float16* xp1 = xp0 + 2048;
    f32x4 e00 = {0.f, 0.f, 0.f, 0.f}, e01 = e00, e10 = e00, e11 = e00;
    #pragma unroll
    for (int s = 0; s < 8; ++s) {
        f16x8 a0, a1;
        if (s < 4) {
            int ho = (s << 5) + (l4 << 3);
            a0 = *(const f16x8*)&Hs[l15][ho];
            a1 = *(const f16x8*)&Hs[16 + l15][ho];
        } else {
            a0 = *(const f16x8*)(xp0 + ((s - 4) << 9));
            a1 = *(const f16x8*)(xp1 + ((s - 4) << 9));
        }
        f16x8 b0 = *(const f16x8*)(wb0 + (s << 9));
        f16x8 b1 = *(const f16x8*)(wb1 + (s << 9));
        e00 = MFMA16(a0, b0, e00);
        e01 = MFMA16(a1, b0, e01);
        e10 = MFMA16(a0, b1, e10);
        e11 = MFMA16(a1, b1, e11);
    }
    int n0 = w * 32 + l15;
    int n1 = n0 + 16;
    float bv0 = bias[n0], bv1 = bias[n1];
    #pragma unroll
    for (int r = 0; r < 4; ++r) {
        int m0r = gmb + (l4 << 2) + r;
        int m1r = m0r + 16;
        float v;
        v = e00[r] + bv0; out[(size_t)m0r * 256 + n0] = v > 0.f ? v : 0.01f * v;
        v = e01[r] + bv0; out[(size_t)m1r * 256 + n0] = v > 0.f ? v : 0.01f * v;
        v = e10[r] + bv1; out[(size_t)m0r * 256 + n1] = v > 0.f ? v : 0.01f * v;
        v = e11[r] + bv1; out[(size_t)m1r * 256 + n1] = v > 0.f ? v : 0.01f * v;
    }
}

extern "C" void kernel_launch(void* const* d_in, const int* in_sizes, int n_in,
                              void* d_out, int out_size, void* d_ws, size_t ws_size,
                              hipStream_t stream) {
    const float* x     = (const float*)d_in[0];
    const int*   ld    = (const int*)d_in[1];
    const float* am    = (const float*)d_in[2];
    const float* Wl    = (const float*)d_in[3];
    const float* bl    = (const float*)d_in[4];
    const float* gl    = (const float*)d_in[5];
    const float* betal = (const float*)d_in[6];
    const float* ml    = (const float*)d_in[7];
    const float* vl    = (const float*)d_in[8];
    const float* W1    = (const float*)d_in[9];
    const float* b1    = (const float*)d_in[10];
    const float* g1    = (const float*)d_in[11];
    const float* beta1 = (const float*)d_in[12];
    const float* m1    = (const float*)d_in[13];
    const float* v1    = (const float*)d_in[14];
    const float* W2    = (const float*)d_in[15];
    const float* b2    = (const float*)d_in[16];
    const float* g2    = (const float*)d_in[17];
    const float* beta2 = (const float*)d_in[18];
    const float* m2    = (const float*)d_in[19];
    const float* v2    = (const float*)d_in[20];
    float* out = (float*)d_out;

    int M = in_sizes[0] / 128;   // 16384
    int n_tasks = M / 32;        // 512

    char* w = (char*)d_ws;
    int*   offs = (int*)(w);                    // 64 int
    float* c1   = (float*)(w + 512);            // 128 f
    float* cf   = (float*)(w + 1024);           // 256 f
    int*   tg   = (int*)(w + 2048);             // 512 int
    int*   tr   = (int*)(w + 4096);             // 512 int
    int*   ta   = (int*)(w + 6144);             // 512 int
    _Float16* W1t = (_Float16*)(w + 16384);     // 32 KB
    _Float16* Wct = (_Float16*)(w + 49152);     // 128 KB
    _Float16* amt = (_Float16*)(w + 180224);    // 10.5 MB
    _Float16* XTt = (_Float16*)(w + 180224 + (size_t)10485760);
    _Float16* xh_t = XTt + (size_t)M * 128;
    _Float16* H2Tt = xh_t + (size_t)M * 128;

    prep_conv_kernel<<<320, 256, 0, stream>>>(ld,
        Wl, bl, gl, betal, ml, vl,
        W1, b1, g1, beta1, m1, v1,
        W2, b2, g2, beta2, m2, v2,
        offs, c1, cf, tg, tr, ta, n_tasks, W1t, Wct, x, XTt, xh_t, M);

    fused1s_kernel<<<n_tasks, 512, 0, stream>>>(am, XTt, ld, offs, tg, tr, ta, W1t, c1, amt, H2Tt);

    fused2s_kernel<<<n_tasks, 512, 0, stream>>>(amt, H2Tt, ld, offs, tg, tr, ta, xh_t, Wct, cf, out);
}

// Round 22
// 36.687 us; speedup vs baseline: 1.1530x; 1.1530x over previous
//
#include <hip/hip_runtime.h>

#define EPS 1e-5f

typedef __attribute__((ext_vector_type(4))) float f32x4;
typedef __attribute__((ext_vector_type(8))) _Float16 f16x8;
typedef __attribute__((ext_vector_type(4))) _Float16 f16x4;

// fragment-ordered tiled index: row r (16-tiled), col k (32-tiled), K = row length.
__device__ __forceinline__ int tidx(int r, int k, int K) {
    return (r >> 4) * (K << 4) + ((k >> 5) << 9) + ((r & 15) << 5) + (((k & 31) >> 3) << 3) + (k & 7);
}

#define MFMA16(a, b, c) __builtin_amdgcn_mfma_f32_16x16x32_f16(a, b, c, 0, 0, 0)

// LPT slot -> (graph, row): 64 slots per 8-graph chunk; 0-47 long (l=384), 48-63 short.
__device__ __forceinline__ void slot_map(int s, int& g, int& r0) {
    int c = s >> 6, j = s & 63;
    if (j < 48) { g = c * 8 + 2 * (j / 12) + 1; r0 = (j % 12) << 5; }
    else        { int jj = j - 48; g = c * 8 + 2 * (jj / 4); r0 = (jj % 4) << 5; }
}

// ============ kernel 1: prep (identical to round-20 champion) ============
__global__ __launch_bounds__(256) void prep_conv_kernel(
    const int* __restrict__ ld, const float* __restrict__ am,
    const float* __restrict__ Wl, const float* __restrict__ bl,
    const float* __restrict__ gl, const float* __restrict__ betal,
    const float* __restrict__ ml, const float* __restrict__ vl,
    const float* __restrict__ W1, const float* __restrict__ b1,
    const float* __restrict__ g1, const float* __restrict__ beta1,
    const float* __restrict__ m1, const float* __restrict__ v1,
    const float* __restrict__ W2, const float* __restrict__ b2,
    const float* __restrict__ g2, const float* __restrict__ beta2,
    const float* __restrict__ m2, const float* __restrict__ v2,
    int* __restrict__ offs, float* __restrict__ c1, float* __restrict__ cf,
    int* __restrict__ tg, int* __restrict__ tr, int* __restrict__ ta, int n_tasks,
    _Float16* __restrict__ W1t, _Float16* __restrict__ Wct,
    _Float16* __restrict__ amt,
    const float* __restrict__ x, _Float16* __restrict__ XTt,
    _Float16* __restrict__ xh_t, int M)
{
    __shared__ __align__(16) _Float16 Tt[128][80];
    int t = threadIdx.x;
    if (blockIdx.x < 256) {
        int m0 = blockIdx.x * 64;
        int gg = 0, off = 0;
        while (m0 >= off + ld[gg]) { off += ld[gg]; ++gg; }
        int l = ld[gg];
        #pragma unroll
        for (int p = 0; p < 8; ++p) {
            int idx = t + p * 256;
            int m = idx >> 5;
            int f = (idx & 31) * 4;
            float4 v = *(const float4*)&x[(size_t)(m0 + m) * 128 + f];
            Tt[f + 0][m] = (_Float16)v.x; Tt[f + 1][m] = (_Float16)v.y;
            Tt[f + 2][m] = (_Float16)v.z; Tt[f + 3][m] = (_Float16)v.w;
            f16x4 h;
            h[0] = (_Float16)v.x; h[1] = (_Float16)v.y;
            h[2] = (_Float16)v.z; h[3] = (_Float16)v.w;
            *(f16x4*)&xh_t[tidx(m0 + m, f, 128)] = h;
        }
        __syncthreads();
        #pragma unroll
        for (int p = 0; p < 4; ++p) {
            int idx = t + p * 256;
            int f = idx >> 3;
            int m8 = (idx & 7) * 8;
            int kl = m0 - off + m8;
            uint4 v = *(const uint4*)&Tt[f][m8];
            *(uint4*)&XTt[off * 128 + tidx(f, kl, l)] = v;
        }
    } else if (blockIdx.x < 320) {
        int b = blockIdx.x - 256;
        int gt = b * 256 + t;
        const int gsize = 64 * 256;
        if (b == 0) {
            if (t < 64) {
                int s = 0;
                for (int i = 0; i < t; ++i) s += ld[i];
                offs[t] = s;
            }
            if (t < 128) {
                float s1 = g1[t] * rsqrtf(v1[t] + EPS);
                c1[t] = (b1[t] - m1[t]) * s1 + beta1[t];
            }
            if (t < 256) {
                float s2 = g2[t] * rsqrtf(v2[t] + EPS);
                float sl = gl[t] * rsqrtf(vl[t] + EPS);
                cf[t] = (b2[t] - m2[t]) * s2 + beta2[t] + (bl[t] - ml[t]) * sl + betal[t];
            }
            for (int s = t; s < n_tasks; s += 256) {
                int g, r0;
                slot_map(s, g, r0);
                int amo = 0;
                for (int gg2 = 0; gg2 < g; ++gg2) { int L = ld[gg2]; amo += L * L; }
                tg[s] = g;
                tr[s] = r0;
                ta[s] = amo;
            }
        }
        for (int idx = gt; idx < 128 * 128; idx += gsize) {
            int n = idx >> 7, k = idx & 127;
            float s1 = g1[n] * rsqrtf(v1[n] + EPS);
            W1t[tidx(n, k, 128)] = (_Float16)(W1[idx] * s1);
        }
        for (int idx = gt; idx < 256 * 256; idx += gsize) {
            int n = idx >> 8, k = idx & 255;
            float v;
            if (k < 128) {
                float s2 = g2[n] * rsqrtf(v2[n] + EPS);
                v = W2[n * 128 + k] * s2;
            } else {
                float sl = gl[n] * rsqrtf(vl[n] + EPS);
                v = Wl[n * 128 + (k - 128)] * sl;
            }
            Wct[tidx(n, k, 256)] = (_Float16)v;
        }
    } else {
        int b2 = blockIdx.x - 320;
        int s = ((b2 & 7) << 6) + (b2 >> 3);
        int g, r0;
        slot_map(s, g, r0);
        int amo = 0;
        for (int gg2 = 0; gg2 < g; ++gg2) { int L = ld[gg2]; amo += L * L; }
        int l = ld[g];
        const float* src = am + (size_t)g * (512 * 512);
        _Float16* dst = amt + amo;
        int lq = l >> 2;
        int tot = lq << 5;
        for (int q = t; q < tot; q += 256) {
            int row = q / lq;
            int c4 = (q - row * lq) << 2;
            float4 v = *(const float4*)&src[(size_t)(r0 + row) * 512 + c4];
            f16x4 h;
            h[0] = (_Float16)v.x; h[1] = (_Float16)v.y;
            h[2] = (_Float16)v.z; h[3] = (_Float16)v.w;
            *(f16x4*)&dst[tidx(r0 + row, c4, l)] = h;
        }
    }
}

// staged phase A, BK=64: per buffer fill, 2 k-steps staged (A 16 KB, B 4 KB);
// 1 barrier per 2 k-steps; 8 waves each do 2x(1 A-frag + 2 B-frags -> 2 MFMA).
#define STAGED64()                                                            \
    {                                                                         \
        uint4 a0 = *(const uint4*)(sa);                                       \
        uint4 a1 = *(const uint4*)(sa + 512);                                 \
        uint4 b0v, b1v;                                                       \
        if (isB) { b0v = *(const uint4*)(sb); b1v = *(const uint4*)(sb + 512); } \
        *(uint4*)&Ast[0][dstA] = a0;                                          \
        *(uint4*)&Ast[0][4096 + dstA] = a1;                                   \
        if (isB) {                                                            \
            *(uint4*)&Bst[0][dstB] = b0v;                                     \
            *(uint4*)&Bst[0][1024 + dstB] = b1v;                              \
        }                                                                     \
        __syncthreads();                                                      \
        int cur = 0;                                                          \
        for (int s = 0; s < nk; s += 2) {                                     \
            uint4 na0, na1, nb0, nb1;                                         \
            if (s + 2 < nk) {                                                 \
                na0 = *(const uint4*)(sa + ((s + 2) << 9));                   \
                na1 = *(const uint4*)(sa + ((s + 3) << 9));                   \
                if (isB) {                                                    \
                    nb0 = *(const uint4*)(sb + ((s + 2) << 9));               \
                    nb1 = *(const uint4*)(sb + ((s + 3) << 9));               \
                }                                                             \
            }                                                                 \
            {                                                                 \
                f16x8 a   = *(const f16x8*)&Ast[cur][(w << 9) + rdo];         \
                f16x8 bb0 = *(const f16x8*)&Bst[cur][rdo];                    \
                f16x8 bb1 = *(const f16x8*)&Bst[cur][512 + rdo];              \
                acc0 = MFMA16(a, bb0, acc0);                                  \
                acc1 = MFMA16(a, bb1, acc1);                                  \
            }                                                                 \
            {                                                                 \
                f16x8 a   = *(const f16x8*)&Ast[cur][4096 + (w << 9) + rdo];  \
                f16x8 bb0 = *(const f16x8*)&Bst[cur][1024 + rdo];             \
                f16x8 bb1 = *(const f16x8*)&Bst[cur][1536 + rdo];             \
                acc0 = MFMA16(a, bb0, acc0);                                  \
                acc1 = MFMA16(a, bb1, acc1);                                  \
            }                                                                 \
            if (s + 2 < nk) {                                                 \
                int nxt = cur ^ 1;                                            \
                *(uint4*)&Ast[nxt][dstA] = na0;                               \
                *(uint4*)&Ast[nxt][4096 + dstA] = na1;                        \
                if (isB) {                                                    \
                    *(uint4*)&Bst[nxt][dstB] = nb0;                           \
                    *(uint4*)&Bst[nxt][1024 + dstB] = nb1;                    \
                }                                                             \
                __syncthreads();                                              \
                cur = nxt;                                                    \
            }                                                                 \
        }                                                                     \
    }

// ============ kernel 2: fused agg1 + lin1 -> H2Tt (staged BK=64, 32-row tasks, 8 waves) ============
__global__ __launch_bounds__(512) void fused1s_kernel(
    const _Float16* __restrict__ amt, const _Float16* __restrict__ XTt,
    const int* __restrict__ ld, const int* __restrict__ offs,
    const int* __restrict__ tg, const int* __restrict__ tr, const int* __restrict__ ta,
    const _Float16* __restrict__ W1t, const float* __restrict__ bias,
    _Float16* __restrict__ H2Tt)
{
    int task = ((blockIdx.x & 7) << 6) + (blockIdx.x >> 3);
    int g = tg[task];
    int l = ld[g];
    int off = offs[g];

    int tid = threadIdx.x;
    int lane = tid & 63;
    int w = tid >> 6;            // 0..7 = A-feat-tile
    int l15 = lane & 15;
    int l4 = lane >> 4;

    __shared__ __align__(16) _Float16 Ast[2][8192];
    __shared__ __align__(16) _Float16 Bst[2][2048];
    __shared__ __align__(16) _Float16 Hs[32][136];

    const int ts = l << 4;
    const int nk = l >> 5;                       // 4 or 12
    const int lane_off = (l15 << 5) + (l4 << 3);
    const int rdo = lane_off ^ ((l15 & 7) << 3); // swizzled read offset

    int idx63 = tid & 63;
    int wr = idx63 >> 2, wc = idx63 & 3;
    int wt = (wr << 5) + (wc << 3);
    int wts = wt ^ ((wr & 7) << 3);
    const int dstA = ((tid >> 6) << 9) + wts;
    const int dstB = (((tid >> 6) & 1) << 9) + wts;
    const bool isB = tid < 128;

    const _Float16* sa = XTt + off * 128 + (tid >> 6) * ts + (idx63 << 3);
    const _Float16* sb = amt + ta[task]
        + ((tr[task] >> 4) + ((tid >> 6) & 1)) * ts + (idx63 << 3);

    f32x4 acc0 = {0.f, 0.f, 0.f, 0.f}, acc1 = acc0;
    STAGED64()

    // spill h1: feat = w*16 + l4*4 + r; rows l15 (acc0) / 16+l15 (acc1)
    {
        f16x4 o0, o1;
        #pragma unroll
        for (int r = 0; r < 4; ++r) { o0[r] = (_Float16)acc0[r]; o1[r] = (_Float16)acc1[r]; }
        *(f16x4*)&Hs[l15][w * 16 + (l4 << 2)] = o0;
        *(f16x4*)&Hs[16 + l15][w * 16 + (l4 << 2)] = o1;
    }
    __syncthreads();

    // phase B: K=128, wave w owns out-feat tile w (16 feats), 32 rows
    const _Float16* wbase = W1t + w * 2048 + lane_off;
    f32x4 e0 = {0.f, 0.f, 0.f, 0.f}, e1 = e0;
    #pragma unroll
    for (int s = 0; s < 4; ++s) {
        int ho = (s << 5) + (l4 << 3);
        f16x8 a0 = *(const f16x8*)&Hs[l15][ho];
        f16x8 a1 = *(const f16x8*)&Hs[16 + l15][ho];
        f16x8 b  = *(const f16x8*)(wbase + (s << 9));
        e0 = MFMA16(a0, b, e0);
        e1 = MFMA16(a1, b, e1);
    }
    int hb = off * 128;
    int trb = tr[task];
    int n = w * 16 + l15;
    float bv = bias[n];
    {
        f16x4 o;
        #pragma unroll
        for (int r = 0; r < 4; ++r) {
            float v = e0[r] + bv;
            o[r] = (_Float16)(v > 0.f ? v : 0.f);
        }
        *(f16x4*)&H2Tt[hb + tidx(n, trb + (l4 << 2), l)] = o;
    }
    {
        f16x4 o;
        #pragma unroll
        for (int r = 0; r < 4; ++r) {
            float v = e1[r] + bv;
            o[r] = (_Float16)(v > 0.f ? v : 0.f);
        }
        *(f16x4*)&H2Tt[hb + tidx(n, trb + 16 + (l4 << 2), l)] = o;
    }
}

// ============ kernel 3: fused agg2 + final -> out fp32 (staged BK=64, 32-row tasks, 8 waves) ============
__global__ __launch_bounds__(512) void fused2s_kernel(
    const _Float16* __restrict__ amt, const _Float16* __restrict__ H2Tt,
    const int* __restrict__ ld, const int* __restrict__ offs,
    const int* __restrict__ tg, const int* __restrict__ tr, const int* __restrict__ ta,
    const _Float16* __restrict__ xh_t, const _Float16* __restrict__ Wct,
    const float* __restrict__ bias, float* __restrict__ out)
{
    int task = ((blockIdx.x & 7) << 6) + (blockIdx.x >> 3);
    int g = tg[task];
    int l = ld[g];
    int off = offs[g];

    int tid = threadIdx.x;
    int lane = tid & 63;
    int w = tid >> 6;
    int l15 = lane & 15;
    int l4 = lane >> 4;

    __shared__ __align__(16) _Float16 Ast[2][8192];
    __shared__ __align__(16) _Float16 Bst[2][2048];
    __shared__ __align__(16) _Float16 Hs[32][136];

    const int ts = l << 4;
    const int nk = l >> 5;
    const int lane_off = (l15 << 5) + (l4 << 3);
    const int rdo = lane_off ^ ((l15 & 7) << 3);

    int idx63 = tid & 63;
    int wr = idx63 >> 2, wc = idx63 & 3;
    int wt = (wr << 5) + (wc << 3);
    int wts = wt ^ ((wr & 7) << 3);
    const int dstA = ((tid >> 6) << 9) + wts;
    const int dstB = (((tid >> 6) & 1) << 9) + wts;
    const bool isB = tid < 128;

    const _Float16* sa = H2Tt + off * 128 + (tid >> 6) * ts + (idx63 << 3);
    const _Float16* sb = amt + ta[task]
        + ((tr[task] >> 4) + ((tid >> 6) & 1)) * ts + (idx63 << 3);

    f32x4 acc0 = {0.f, 0.f, 0.f, 0.f}, acc1 = acc0;
    STAGED64()

    {
        f16x4 o0, o1;
        #pragma unroll
        for (int r = 0; r < 4; ++r) { o0[r] = (_Float16)acc0[r]; o1[r] = (_Float16)acc1[r]; }
        *(f16x4*)&Hs[l15][w * 16 + (l4 << 2)] = o0;
        *(f16x4*)&Hs[16 + l15][w * 16 + (l4 << 2)] = o1;
    }
    __syncthreads();

    // phase B: K=256 ([h3 | x]), wave w owns out-feat tiles {2w, 2w+1}, 32 rows
    int gmb = off + tr[task];
    const _Float16* wb0 = Wct + (w * 2) * 4096 + lane_off;
    const _Float16* wb1 = wb0 + 4096;
    const _Float16* xp0 = xh_t + (gmb >> 4) * 2048 + lane_off;
    const _Float16* xp1 = xp0 + 2048;
    f32x4 e00 = {0.f, 0.f, 0.f, 0.f}, e01 = e00, e10 = e00, e11 = e00;
    #pragma unroll
    for (int s = 0; s < 8; ++s) {
        f16x8 a0, a1;
        if (s < 4) {
            int ho = (s << 5) + (l4 << 3);
            a0 = *(const f16x8*)&Hs[l15][ho];
            a1 = *(const f16x8*)&Hs[16 + l15][ho];
        } else {
            a0 = *(const f16x8*)(xp0 + ((s - 4) << 9));
            a1 = *(const f16x8*)(xp1 + ((s - 4) << 9));
        }
        f16x8 b0 = *(const f16x8*)(wb0 + (s << 9));
        f16x8 b1 = *(const f16x8*)(wb1 + (s << 9));
        e00 = MFMA16(a0, b0, e00);
        e01 = MFMA16(a1, b0, e01);
        e10 = MFMA16(a0, b1, e10);
        e11 = MFMA16(a1, b1, e11);
    }
    int n0 = w * 32 + l15;
    int n1 = n0 + 16;
    float bv0 = bias[n0], bv1 = bias[n1];
    #pragma unroll
    for (int r = 0; r < 4; ++r) {
        int m0r = gmb + (l4 << 2) + r;
        int m1r = m0r + 16;
        float v;
        v = e00[r] + bv0; out[(size_t)m0r * 256 + n0] = v > 0.f ? v : 0.01f * v;
        v = e01[r] + bv0; out[(size_t)m1r * 256 + n0] = v > 0.f ? v : 0.01f * v;
        v = e10[r] + bv1; out[(size_t)m0r * 256 + n1] = v > 0.f ? v : 0.01f * v;
        v = e11[r] + bv1; out[(size_t)m1r * 256 + n1] = v > 0.f ? v : 0.01f * v;
    }
}

extern "C" void kernel_launch(void* const* d_in, const int* in_sizes, int n_in,
                              void* d_out, int out_size, void* d_ws, size_t ws_size,
                              hipStream_t stream) {
    const float* x     = (const float*)d_in[0];
    const int*   ld    = (const int*)d_in[1];
    const float* am    = (const float*)d_in[2];
    const float* Wl    = (const float*)d_in[3];
    const float* bl    = (const float*)d_in[4];
    const float* gl    = (const float*)d_in[5];
    const float* betal = (const float*)d_in[6];
    const float* ml    = (const float*)d_in[7];
    const float* vl    = (const float*)d_in[8];
    const float* W1    = (const float*)d_in[9];
    const float* b1    = (const float*)d_in[10];
    const float* g1    = (const float*)d_in[11];
    const float* beta1 = (const float*)d_in[12];
    const float* m1    = (const float*)d_in[13];
    const float* v1    = (const float*)d_in[14];
    const float* W2    = (const float*)d_in[15];
    const float* b2    = (const float*)d_in[16];
    const float* g2    = (const float*)d_in[17];
    const float* beta2 = (const float*)d_in[18];
    const float* m2    = (const float*)d_in[19];
    const float* v2    = (const float*)d_in[20];
    float* out = (float*)d_out;

    int M = in_sizes[0] / 128;   // 16384
    int n_tasks = M / 32;        // 512

    char* w = (char*)d_ws;
    int*   offs = (int*)(w);                    // 64 int
    float* c1   = (float*)(w + 512);            // 128 f
    float* cf   = (float*)(w + 1024);           // 256 f
    int*   tg   = (int*)(w + 2048);             // 512 int
    int*   tr   = (int*)(w + 4096);             // 512 int
    int*   ta   = (int*)(w + 6144);             // 512 int
    _Float16* W1t = (_Float16*)(w + 16384);     // 32 KB
    _Float16* Wct = (_Float16*)(w + 49152);     // 128 KB
    _Float16* amt = (_Float16*)(w + 180224);    // 10.5 MB
    _Float16* XTt = (_Float16*)(w + 180224 + (size_t)10485760);
    _Float16* xh_t = XTt + (size_t)M * 128;
    _Float16* H2Tt = xh_t + (size_t)M * 128;

    prep_conv_kernel<<<832, 256, 0, stream>>>(ld, am,
        Wl, bl, gl, betal, ml, vl,
        W1, b1, g1, beta1, m1, v1,
        W2, b2, g2, beta2, m2, v2,
        offs, c1, cf, tg, tr, ta, n_tasks, W1t, Wct, amt, x, XTt, xh_t, M);

    fused1s_kernel<<<n_tasks, 512, 0, stream>>>(amt, XTt, ld, offs, tg, tr, ta, W1t, c1, H2Tt);

    fused2s_kernel<<<n_tasks, 512, 0, stream>>>(amt, H2Tt, ld, offs, tg, tr, ta, xh_t, Wct, cf, out);
}